// Round 6
// baseline (2570.174 us; speedup 1.0000x reference)
//
#include <hip/hip_runtime.h>

#define DIM 64
#define EPS 1e-8f

// ---------------------------------------------------------------------------
// Pipeline (CSR, no float atomics, no h materialization):
//   scan1/2/3 : exclusive scan of degree -> off[] (+cursor copy)
//   sort      : counting sort -> csr cols grouped by row (1 int atomic/edge)
//   gather    : z[i] = deg_i*x[i] + sum x[csr[j]]   -> written to d_out
//   out       : agg = z@fc_w^T + 2*deg*fc_b ; alpha/beta/gamma from x;
//               out = (relu(b)*agg + g)/(relu(a) + relu(b)*deg + EPS)
//
// Algebra: agg[i] = k_i*h[i] + sum h[col] with h = x@W^T + b and k_i ==
// degree[i], so agg[i] = z[i]@W^T + 2*deg_i*b with z = deg*x + sum x[col].
//
// Round-5 lesson (counters): the dual-shfl epilogue fetched 2.78GB (36x the
// useful bytes; spill-through-TCC signature) at VALUBusy 4.4%. This version
// has ZERO cross-lane ops: x/z come as wave-uniform float4 broadcast loads,
// and each weight ds_read_b128 is amortized over 4 nodes (16 FMAs/read).
// ---------------------------------------------------------------------------

__global__ __launch_bounds__(256) void scan1_kernel(
    const float* __restrict__ degree, int* __restrict__ off,
    int* __restrict__ bsum, int n)
{
  __shared__ int s[256];
  const int t = threadIdx.x;
  const int i = blockIdx.x * 256 + t;
  const int v = (i < n) ? (int)(degree[i] + 0.5f) : 0;
  s[t] = v;
  __syncthreads();
  for (int st = 1; st < 256; st <<= 1) {
    int a = (t >= st) ? s[t - st] : 0;
    __syncthreads();
    s[t] += a;
    __syncthreads();
  }
  if (i < n) off[i] = s[t] - v;
  if (t == 255) bsum[blockIdx.x] = s[t];
}

__global__ __launch_bounds__(512) void scan2_kernel(
    const int* __restrict__ bsum, int* __restrict__ bpre,
    int* __restrict__ off, int nb, int ch, int n)
{
  __shared__ int s[512];
  const int t = threadIdx.x;
  const int base = t * ch;
  int local = 0;
  for (int q = 0; q < ch; ++q) {
    const int j = base + q;
    if (j < nb) local += bsum[j];
  }
  s[t] = local;
  __syncthreads();
  for (int st = 1; st < 512; st <<= 1) {
    int a = (t >= st) ? s[t - st] : 0;
    __syncthreads();
    s[t] += a;
    __syncthreads();
  }
  int run = s[t] - local;
  for (int q = 0; q < ch; ++q) {
    const int j = base + q;
    if (j < nb) { bpre[j] = run; run += bsum[j]; }
  }
  if (t == 511) off[n] = s[511];
}

__global__ __launch_bounds__(256) void scan3_kernel(
    int* __restrict__ off, int* __restrict__ cur,
    const int* __restrict__ bpre, int n)
{
  const int i = blockIdx.x * 256 + threadIdx.x;
  if (i < n) {
    const int o = off[i] + bpre[blockIdx.x];
    off[i] = o;
    cur[i] = o;
  }
}

__global__ __launch_bounds__(256) void sort_kernel(
    const int* __restrict__ ei, int* __restrict__ cur,
    int* __restrict__ csr, int E)
{
  const int tid = blockIdx.x * 256 + threadIdx.x;
  const int stride = gridDim.x * 256;
  for (int e = tid; e < E; e += stride) {
    const int r = ei[e];
    const int c = ei[E + e];
    const int p = atomicAdd(&cur[r], 1);
    csr[p] = c;
  }
}

// z[i] = deg_i*x[i] + sum_j x[csr[j]]  — float4 lanes, 4 edges per wave-step.
__global__ __launch_bounds__(256, 8) void gather_kernel(
    const float* __restrict__ x, const int* __restrict__ off,
    const int* __restrict__ csr, const float* __restrict__ degree,
    float* __restrict__ z, int n)
{
  const int lane = threadIdx.x & 63;
  const int sub = lane >> 4;
  const int l16 = lane & 15;
  const int wid = (blockIdx.x << 2) + (threadIdx.x >> 6);
  const int nwaves = gridDim.x << 2;
  for (int node = wid; node < n; node += nwaves) {
    float4 acc = make_float4(0.f, 0.f, 0.f, 0.f);
    if (sub == 0) {
      const float4 xv = *(const float4*)&x[((size_t)node << 6) + (l16 << 2)];
      const float d = degree[node];
      acc.x = d * xv.x; acc.y = d * xv.y; acc.z = d * xv.z; acc.w = d * xv.w;
    }
    const int o0 = off[node];
    const int o1 = off[node + 1];
    int j = o0;
    for (; j + 8 <= o1; j += 8) {
      const int c0 = csr[j + sub];
      const int c1 = csr[j + 4 + sub];
      const float4 v0 = *(const float4*)&x[((size_t)c0 << 6) + (l16 << 2)];
      const float4 v1 = *(const float4*)&x[((size_t)c1 << 6) + (l16 << 2)];
      acc.x += v0.x + v1.x; acc.y += v0.y + v1.y;
      acc.z += v0.z + v1.z; acc.w += v0.w + v1.w;
    }
    if (j + 4 <= o1) {
      const int c = csr[j + sub];
      const float4 v = *(const float4*)&x[((size_t)c << 6) + (l16 << 2)];
      acc.x += v.x; acc.y += v.y; acc.z += v.z; acc.w += v.w;
      j += 4;
    }
    const int rem = o1 - j;
    if (sub < rem) {
      const int c = csr[j + sub];
      const float4 v = *(const float4*)&x[((size_t)c << 6) + (l16 << 2)];
      acc.x += v.x; acc.y += v.y; acc.z += v.z; acc.w += v.w;
    }
    acc.x += __shfl_xor(acc.x, 16, 64); acc.y += __shfl_xor(acc.y, 16, 64);
    acc.z += __shfl_xor(acc.z, 16, 64); acc.w += __shfl_xor(acc.w, 16, 64);
    acc.x += __shfl_xor(acc.x, 32, 64); acc.y += __shfl_xor(acc.y, 32, 64);
    acc.z += __shfl_xor(acc.z, 32, 64); acc.w += __shfl_xor(acc.w, 32, 64);
    if (sub == 0) {
      *(float4*)&z[((size_t)node << 6) + (l16 << 2)] = acc;
    }
  }
}

// Fused epilogue, 4 nodes per wave-iteration, lane = output dim.
// x/z enter via wave-uniform float4 loads (HW broadcast, no bpermute);
// one ds_read_b128 of the interleaved {fc,dir,neu,rob} tile feeds 16 FMAs.
__global__ __launch_bounds__(512, 4) void out_kernel(
    const float* __restrict__ x,
    const float* __restrict__ fc_w,  const float* __restrict__ fc_b,
    const float* __restrict__ dir_w, const float* __restrict__ dir_b,
    const float* __restrict__ neu_w, const float* __restrict__ neu_b,
    const float* __restrict__ rob_w, const float* __restrict__ rob_b,
    const float* __restrict__ degree, float* __restrict__ out, int n)
{
  __shared__ float w_lds[DIM * DIM * 4];
  __shared__ float b_lds[4 * DIM];
  const int t = threadIdx.x;
  for (int i = t; i < DIM * DIM; i += 512) {
    const int d = i >> 6, k = i & 63;
    const int s = (k << 8) | ((d ^ k) << 2);
    w_lds[s + 0] = fc_w[i];
    w_lds[s + 1] = dir_w[i];
    w_lds[s + 2] = neu_w[i];
    w_lds[s + 3] = rob_w[i];
  }
  if (t < DIM) {
    b_lds[t]       = fc_b[t];
    b_lds[64 + t]  = dir_b[t];
    b_lds[128 + t] = neu_b[t];
    b_lds[192 + t] = rob_b[t];
  }
  __syncthreads();

  const int lane = t & 63;
  const float fcb  = b_lds[lane];
  const float dirb = b_lds[64 + lane];
  const float neub = b_lds[128 + lane];
  const float robb = b_lds[192 + lane];

  const int wid = (blockIdx.x << 3) + (t >> 6);
  const int nwaves = gridDim.x << 3;
  const int G = (n + 3) >> 2;                 // node groups of 4
  for (int grp = wid; grp < G; grp += nwaves) {
    const int n0 = grp << 2;
    const int m0 = n0;
    const int m1 = (n0 + 1 < n) ? n0 + 1 : n - 1;   // clamp loads; guard stores
    const int m2 = (n0 + 2 < n) ? n0 + 2 : n - 1;
    const int m3 = (n0 + 3 < n) ? n0 + 3 : n - 1;
    const float* xr0 = x + ((size_t)m0 << 6);
    const float* xr1 = x + ((size_t)m1 << 6);
    const float* xr2 = x + ((size_t)m2 << 6);
    const float* xr3 = x + ((size_t)m3 << 6);
    const float* zr0 = out + ((size_t)m0 << 6);     // z written by gather
    const float* zr1 = out + ((size_t)m1 << 6);
    const float* zr2 = out + ((size_t)m2 << 6);
    const float* zr3 = out + ((size_t)m3 << 6);
    const float d0 = degree[m0], d1 = degree[m1];
    const float d2 = degree[m2], d3 = degree[m3];

    float agg0 = 2.f * d0 * fcb, agg1 = 2.f * d1 * fcb;
    float agg2 = 2.f * d2 * fcb, agg3 = 2.f * d3 * fcb;
    float a0 = dirb, a1 = dirb, a2 = dirb, a3 = dirb;
    float be0 = neub, be1 = neub, be2 = neub, be3 = neub;
    float g0 = robb, g1 = robb, g2 = robb, g3 = robb;

#pragma unroll
    for (int k4 = 0; k4 < 16; ++k4) {
      const float4 xA = *(const float4*)&xr0[k4 << 2];   // wave-uniform
      const float4 xB = *(const float4*)&xr1[k4 << 2];
      const float4 xC = *(const float4*)&xr2[k4 << 2];
      const float4 xD = *(const float4*)&xr3[k4 << 2];
      const float4 zA = *(const float4*)&zr0[k4 << 2];
      const float4 zB = *(const float4*)&zr1[k4 << 2];
      const float4 zC = *(const float4*)&zr2[k4 << 2];
      const float4 zD = *(const float4*)&zr3[k4 << 2];
#pragma unroll
      for (int j = 0; j < 4; ++j) {
        const int k = (k4 << 2) + j;
        const float4 w = *(const float4*)&w_lds[(k << 8) | ((lane ^ k) << 2)];
        const float xa = j == 0 ? xA.x : j == 1 ? xA.y : j == 2 ? xA.z : xA.w;
        const float xb = j == 0 ? xB.x : j == 1 ? xB.y : j == 2 ? xB.z : xB.w;
        const float xc = j == 0 ? xC.x : j == 1 ? xC.y : j == 2 ? xC.z : xC.w;
        const float xd = j == 0 ? xD.x : j == 1 ? xD.y : j == 2 ? xD.z : xD.w;
        const float za = j == 0 ? zA.x : j == 1 ? zA.y : j == 2 ? zA.z : zA.w;
        const float zb = j == 0 ? zB.x : j == 1 ? zB.y : j == 2 ? zB.z : zB.w;
        const float zc = j == 0 ? zC.x : j == 1 ? zC.y : j == 2 ? zC.z : zC.w;
        const float zd = j == 0 ? zD.x : j == 1 ? zD.y : j == 2 ? zD.z : zD.w;
        agg0 = fmaf(za, w.x, agg0); a0 = fmaf(xa, w.y, a0);
        be0  = fmaf(xa, w.z, be0);  g0 = fmaf(xa, w.w, g0);
        agg1 = fmaf(zb, w.x, agg1); a1 = fmaf(xb, w.y, a1);
        be1  = fmaf(xb, w.z, be1);  g1 = fmaf(xb, w.w, g1);
        agg2 = fmaf(zc, w.x, agg2); a2 = fmaf(xc, w.y, a2);
        be2  = fmaf(xc, w.z, be2);  g2 = fmaf(xc, w.w, g2);
        agg3 = fmaf(zd, w.x, agg3); a3 = fmaf(xd, w.y, a3);
        be3  = fmaf(xd, w.z, be3);  g3 = fmaf(xd, w.w, g3);
      }
    }
    a0 = fmaxf(a0, 0.f); be0 = fmaxf(be0, 0.f);
    a1 = fmaxf(a1, 0.f); be1 = fmaxf(be1, 0.f);
    a2 = fmaxf(a2, 0.f); be2 = fmaxf(be2, 0.f);
    a3 = fmaxf(a3, 0.f); be3 = fmaxf(be3, 0.f);
    const float r0 = fmaf(be0, agg0, g0) / (fmaf(be0, d0, a0) + EPS);
    const float r1 = fmaf(be1, agg1, g1) / (fmaf(be1, d1, a1) + EPS);
    const float r2 = fmaf(be2, agg2, g2) / (fmaf(be2, d2, a2) + EPS);
    const float r3 = fmaf(be3, agg3, g3) / (fmaf(be3, d3, a3) + EPS);
    out[((size_t)m0 << 6) | lane] = r0;
    if (n0 + 1 < n) out[((size_t)(n0 + 1) << 6) | lane] = r1;
    if (n0 + 2 < n) out[((size_t)(n0 + 2) << 6) | lane] = r2;
    if (n0 + 3 < n) out[((size_t)(n0 + 3) << 6) | lane] = r3;
  }
}

extern "C" void kernel_launch(void* const* d_in, const int* in_sizes, int n_in,
                              void* d_out, int out_size, void* d_ws, size_t ws_size,
                              hipStream_t stream) {
  const float* x      = (const float*)d_in[0];
  const int*   ei     = (const int*)  d_in[1];
  const float* degree = (const float*)d_in[2];
  const float* fc_w   = (const float*)d_in[3];
  const float* fc_b   = (const float*)d_in[4];
  const float* dir_w  = (const float*)d_in[5];
  const float* dir_b  = (const float*)d_in[6];
  const float* neu_w  = (const float*)d_in[7];
  const float* neu_b  = (const float*)d_in[8];
  const float* rob_w  = (const float*)d_in[9];
  const float* rob_b  = (const float*)d_in[10];
  float* out = (float*)d_out;

  const int n = in_sizes[0] / DIM;
  const int E = in_sizes[1] / 2;
  const int NB = (n + 255) / 256;
  const int CH = (NB + 511) / 512;

  // ws layout: csr | off | cur | bsum | bpre  (~7.8 MB)
  int* csr  = (int*)d_ws;
  int* off  = csr + E;
  int* cur  = off + (n + 1);
  int* bsum = cur + n;
  int* bpre = bsum + NB;

  hipLaunchKernelGGL(scan1_kernel, dim3(NB), dim3(256), 0, stream,
                     degree, off, bsum, n);
  hipLaunchKernelGGL(scan2_kernel, dim3(1), dim3(512), 0, stream,
                     bsum, bpre, off, NB, CH, n);
  hipLaunchKernelGGL(scan3_kernel, dim3(NB), dim3(256), 0, stream,
                     off, cur, bpre, n);
  hipLaunchKernelGGL(sort_kernel, dim3(4096), dim3(256), 0, stream,
                     ei, cur, csr, E);
  hipLaunchKernelGGL(gather_kernel, dim3(2048), dim3(256), 0, stream,
                     x, off, csr, degree, out, n);
  hipLaunchKernelGGL(out_kernel, dim3(512), dim3(512), 0, stream,
                     x, fc_w, fc_b, dir_w, dir_b, neu_w, neu_b, rob_w, rob_b,
                     degree, out, n);
}

// Round 7
// 598.167 us; speedup vs baseline: 4.2967x; 4.2967x over previous
//
#include <hip/hip_runtime.h>

#define DIM 64
#define EPS 1e-8f

// ---------------------------------------------------------------------------
// Pipeline (CSR, no float atomics, no h materialization):
//   scan1/2/3 : exclusive scan of degree -> off[] (+cursor copy)
//   sort      : counting sort -> csr cols grouped by row (1 int atomic/edge)
//   gather    : z[i] = deg_i*x[i] + sum x[csr[j]]   -> written to d_out
//   out       : agg = z@fc_w^T + 2*deg*fc_b ; alpha/beta/gamma from x;
//               out = (relu(b)*agg + g)/(relu(a) + relu(b)*deg + EPS)
//
// Algebra: agg[i] = k_i*h[i] + sum h[col] with h = x@W^T + b and k_i ==
// degree[i], so agg[i] = z[i]@W^T + 2*deg_i*b with z = deg*x + sum x[col].
//
// Round-5/6 lesson (counters): __launch_bounds__(512,4) capped VGPR=64 while
// the 4-node epilogue loop needs ~110 live regs -> per-lane scratch spill ->
// 4.3GB FETCH + 2.3GB WRITE (85x useful bytes) at VALUBusy 2%. Fix: no
// occupancy cap (256-thr blocks, default VGPR budget) + single base pointer
// with compile-time row offsets (0/64/128/192) so address regs don't bloat.
// ---------------------------------------------------------------------------

__global__ __launch_bounds__(256) void scan1_kernel(
    const float* __restrict__ degree, int* __restrict__ off,
    int* __restrict__ bsum, int n)
{
  __shared__ int s[256];
  const int t = threadIdx.x;
  const int i = blockIdx.x * 256 + t;
  const int v = (i < n) ? (int)(degree[i] + 0.5f) : 0;
  s[t] = v;
  __syncthreads();
  for (int st = 1; st < 256; st <<= 1) {
    int a = (t >= st) ? s[t - st] : 0;
    __syncthreads();
    s[t] += a;
    __syncthreads();
  }
  if (i < n) off[i] = s[t] - v;
  if (t == 255) bsum[blockIdx.x] = s[t];
}

__global__ __launch_bounds__(512) void scan2_kernel(
    const int* __restrict__ bsum, int* __restrict__ bpre,
    int* __restrict__ off, int nb, int ch, int n)
{
  __shared__ int s[512];
  const int t = threadIdx.x;
  const int base = t * ch;
  int local = 0;
  for (int q = 0; q < ch; ++q) {
    const int j = base + q;
    if (j < nb) local += bsum[j];
  }
  s[t] = local;
  __syncthreads();
  for (int st = 1; st < 512; st <<= 1) {
    int a = (t >= st) ? s[t - st] : 0;
    __syncthreads();
    s[t] += a;
    __syncthreads();
  }
  int run = s[t] - local;
  for (int q = 0; q < ch; ++q) {
    const int j = base + q;
    if (j < nb) { bpre[j] = run; run += bsum[j]; }
  }
  if (t == 511) off[n] = s[511];
}

__global__ __launch_bounds__(256) void scan3_kernel(
    int* __restrict__ off, int* __restrict__ cur,
    const int* __restrict__ bpre, int n)
{
  const int i = blockIdx.x * 256 + threadIdx.x;
  if (i < n) {
    const int o = off[i] + bpre[blockIdx.x];
    off[i] = o;
    cur[i] = o;
  }
}

__global__ __launch_bounds__(256) void sort_kernel(
    const int* __restrict__ ei, int* __restrict__ cur,
    int* __restrict__ csr, int E)
{
  const int tid = blockIdx.x * 256 + threadIdx.x;
  const int stride = gridDim.x * 256;
  for (int e = tid; e < E; e += stride) {
    const int r = ei[e];
    const int c = ei[E + e];
    const int p = atomicAdd(&cur[r], 1);
    csr[p] = c;
  }
}

// z[i] = deg_i*x[i] + sum_j x[csr[j]]  — float4 lanes, 4 edges per wave-step.
__global__ __launch_bounds__(256, 8) void gather_kernel(
    const float* __restrict__ x, const int* __restrict__ off,
    const int* __restrict__ csr, const float* __restrict__ degree,
    float* __restrict__ z, int n)
{
  const int lane = threadIdx.x & 63;
  const int sub = lane >> 4;
  const int l16 = lane & 15;
  const int wid = (blockIdx.x << 2) + (threadIdx.x >> 6);
  const int nwaves = gridDim.x << 2;
  for (int node = wid; node < n; node += nwaves) {
    float4 acc = make_float4(0.f, 0.f, 0.f, 0.f);
    if (sub == 0) {
      const float4 xv = *(const float4*)&x[((size_t)node << 6) + (l16 << 2)];
      const float d = degree[node];
      acc.x = d * xv.x; acc.y = d * xv.y; acc.z = d * xv.z; acc.w = d * xv.w;
    }
    const int o0 = off[node];
    const int o1 = off[node + 1];
    int j = o0;
    for (; j + 8 <= o1; j += 8) {
      const int c0 = csr[j + sub];
      const int c1 = csr[j + 4 + sub];
      const float4 v0 = *(const float4*)&x[((size_t)c0 << 6) + (l16 << 2)];
      const float4 v1 = *(const float4*)&x[((size_t)c1 << 6) + (l16 << 2)];
      acc.x += v0.x + v1.x; acc.y += v0.y + v1.y;
      acc.z += v0.z + v1.z; acc.w += v0.w + v1.w;
    }
    if (j + 4 <= o1) {
      const int c = csr[j + sub];
      const float4 v = *(const float4*)&x[((size_t)c << 6) + (l16 << 2)];
      acc.x += v.x; acc.y += v.y; acc.z += v.z; acc.w += v.w;
      j += 4;
    }
    const int rem = o1 - j;
    if (sub < rem) {
      const int c = csr[j + sub];
      const float4 v = *(const float4*)&x[((size_t)c << 6) + (l16 << 2)];
      acc.x += v.x; acc.y += v.y; acc.z += v.z; acc.w += v.w;
    }
    acc.x += __shfl_xor(acc.x, 16, 64); acc.y += __shfl_xor(acc.y, 16, 64);
    acc.z += __shfl_xor(acc.z, 16, 64); acc.w += __shfl_xor(acc.w, 16, 64);
    acc.x += __shfl_xor(acc.x, 32, 64); acc.y += __shfl_xor(acc.y, 32, 64);
    acc.z += __shfl_xor(acc.z, 32, 64); acc.w += __shfl_xor(acc.w, 32, 64);
    if (sub == 0) {
      *(float4*)&z[((size_t)node << 6) + (l16 << 2)] = acc;
    }
  }
}

#define SEL4(v, j) ((j) == 0 ? (v).x : (j) == 1 ? (v).y : (j) == 2 ? (v).z : (v).w)

// Fused epilogue, 4 nodes per wave-iteration, lane = output dim.
// x/z enter via wave-uniform float4 loads (HW broadcast); row offsets are
// compile-time (0/64/128/192 elems) off ONE base pointer -> no addr bloat.
// One ds_read_b128 of the interleaved {fc,dir,neu,rob} tile feeds 16 FMAs.
// NO occupancy cap: compiler allocates the ~90 VGPRs the loop needs (the
// round-5/6 spill disaster came from capping this at 64).
__global__ __launch_bounds__(256) void out_kernel(
    const float* __restrict__ x,
    const float* __restrict__ fc_w,  const float* __restrict__ fc_b,
    const float* __restrict__ dir_w, const float* __restrict__ dir_b,
    const float* __restrict__ neu_w, const float* __restrict__ neu_b,
    const float* __restrict__ rob_w, const float* __restrict__ rob_b,
    const float* __restrict__ degree, float* __restrict__ out, int n)
{
  __shared__ float w_lds[DIM * DIM * 4];
  __shared__ float b_lds[4 * DIM];
  const int t = threadIdx.x;
  for (int i = t; i < DIM * DIM; i += 256) {
    const int d = i >> 6, k = i & 63;
    const int s = (k << 8) | ((d ^ k) << 2);
    w_lds[s + 0] = fc_w[i];
    w_lds[s + 1] = dir_w[i];
    w_lds[s + 2] = neu_w[i];
    w_lds[s + 3] = rob_w[i];
  }
  if (t < DIM) {
    b_lds[t]       = fc_b[t];
    b_lds[64 + t]  = dir_b[t];
    b_lds[128 + t] = neu_b[t];
    b_lds[192 + t] = rob_b[t];
  }
  __syncthreads();

  const int lane = t & 63;
  const float fcb  = b_lds[lane];
  const float dirb = b_lds[64 + lane];
  const float neub = b_lds[128 + lane];
  const float robb = b_lds[192 + lane];

  const int wid = (blockIdx.x << 2) + (t >> 6);
  const int nwaves = gridDim.x << 2;
  const int Gfull = n >> 2;                    // full groups of 4 nodes

  for (int grp = wid; grp < Gfull; grp += nwaves) {
    const int n0 = grp << 2;
    const float* xr = x + ((size_t)n0 << 6);
    const float* zr = out + ((size_t)n0 << 6);   // z written by gather
    const float d0 = degree[n0],     d1 = degree[n0 + 1];
    const float d2 = degree[n0 + 2], d3 = degree[n0 + 3];

    float agg0 = 2.f * d0 * fcb, agg1 = 2.f * d1 * fcb;
    float agg2 = 2.f * d2 * fcb, agg3 = 2.f * d3 * fcb;
    float a0 = dirb, a1 = dirb, a2 = dirb, a3 = dirb;
    float be0 = neub, be1 = neub, be2 = neub, be3 = neub;
    float g0 = robb, g1 = robb, g2 = robb, g3 = robb;

#pragma unroll
    for (int k4 = 0; k4 < 16; ++k4) {
      // row r lives at element offset r*64 (compile-time) from the base
      const float4 xA = *(const float4*)&xr[(k4 << 2)];
      const float4 xB = *(const float4*)&xr[(k4 << 2) + 64];
      const float4 xC = *(const float4*)&xr[(k4 << 2) + 128];
      const float4 xD = *(const float4*)&xr[(k4 << 2) + 192];
      const float4 zA = *(const float4*)&zr[(k4 << 2)];
      const float4 zB = *(const float4*)&zr[(k4 << 2) + 64];
      const float4 zC = *(const float4*)&zr[(k4 << 2) + 128];
      const float4 zD = *(const float4*)&zr[(k4 << 2) + 192];
#pragma unroll
      for (int j = 0; j < 4; ++j) {
        const int k = (k4 << 2) + j;
        const float4 w = *(const float4*)&w_lds[(k << 8) | ((lane ^ k) << 2)];
        agg0 = fmaf(SEL4(zA, j), w.x, agg0); a0 = fmaf(SEL4(xA, j), w.y, a0);
        be0  = fmaf(SEL4(xA, j), w.z, be0);  g0 = fmaf(SEL4(xA, j), w.w, g0);
        agg1 = fmaf(SEL4(zB, j), w.x, agg1); a1 = fmaf(SEL4(xB, j), w.y, a1);
        be1  = fmaf(SEL4(xB, j), w.z, be1);  g1 = fmaf(SEL4(xB, j), w.w, g1);
        agg2 = fmaf(SEL4(zC, j), w.x, agg2); a2 = fmaf(SEL4(xC, j), w.y, a2);
        be2  = fmaf(SEL4(xC, j), w.z, be2);  g2 = fmaf(SEL4(xC, j), w.w, g2);
        agg3 = fmaf(SEL4(zD, j), w.x, agg3); a3 = fmaf(SEL4(xD, j), w.y, a3);
        be3  = fmaf(SEL4(xD, j), w.z, be3);  g3 = fmaf(SEL4(xD, j), w.w, g3);
      }
    }
    a0 = fmaxf(a0, 0.f); be0 = fmaxf(be0, 0.f);
    a1 = fmaxf(a1, 0.f); be1 = fmaxf(be1, 0.f);
    a2 = fmaxf(a2, 0.f); be2 = fmaxf(be2, 0.f);
    a3 = fmaxf(a3, 0.f); be3 = fmaxf(be3, 0.f);
    const float r0 = fmaf(be0, agg0, g0) / (fmaf(be0, d0, a0) + EPS);
    const float r1 = fmaf(be1, agg1, g1) / (fmaf(be1, d1, a1) + EPS);
    const float r2 = fmaf(be2, agg2, g2) / (fmaf(be2, d2, a2) + EPS);
    const float r3 = fmaf(be3, agg3, g3) / (fmaf(be3, d3, a3) + EPS);
    out[((size_t)n0 << 6) | lane] = r0;
    out[((size_t)(n0 + 1) << 6) | lane] = r1;
    out[((size_t)(n0 + 2) << 6) | lane] = r2;
    out[((size_t)(n0 + 3) << 6) | lane] = r3;
  }

  // tail (n % 4 nodes): one wave handles them with the simple per-node path
  if (blockIdx.x == 0 && (t >> 6) == 0) {
    for (int node = Gfull << 2; node < n; ++node) {
      const float* xr = x + ((size_t)node << 6);
      const float* zr = out + ((size_t)node << 6);
      const float d0 = degree[node];
      float agg = 2.f * d0 * fcb;
      float a = dirb, be = neub, g = robb;
#pragma unroll
      for (int k4 = 0; k4 < 16; ++k4) {
        const float4 xA = *(const float4*)&xr[(k4 << 2)];
        const float4 zA = *(const float4*)&zr[(k4 << 2)];
#pragma unroll
        for (int j = 0; j < 4; ++j) {
          const int k = (k4 << 2) + j;
          const float4 w = *(const float4*)&w_lds[(k << 8) | ((lane ^ k) << 2)];
          agg = fmaf(SEL4(zA, j), w.x, agg);
          a   = fmaf(SEL4(xA, j), w.y, a);
          be  = fmaf(SEL4(xA, j), w.z, be);
          g   = fmaf(SEL4(xA, j), w.w, g);
        }
      }
      a = fmaxf(a, 0.f); be = fmaxf(be, 0.f);
      out[((size_t)node << 6) | lane] =
          fmaf(be, agg, g) / (fmaf(be, d0, a) + EPS);
    }
  }
}

extern "C" void kernel_launch(void* const* d_in, const int* in_sizes, int n_in,
                              void* d_out, int out_size, void* d_ws, size_t ws_size,
                              hipStream_t stream) {
  const float* x      = (const float*)d_in[0];
  const int*   ei     = (const int*)  d_in[1];
  const float* degree = (const float*)d_in[2];
  const float* fc_w   = (const float*)d_in[3];
  const float* fc_b   = (const float*)d_in[4];
  const float* dir_w  = (const float*)d_in[5];
  const float* dir_b  = (const float*)d_in[6];
  const float* neu_w  = (const float*)d_in[7];
  const float* neu_b  = (const float*)d_in[8];
  const float* rob_w  = (const float*)d_in[9];
  const float* rob_b  = (const float*)d_in[10];
  float* out = (float*)d_out;

  const int n = in_sizes[0] / DIM;
  const int E = in_sizes[1] / 2;
  const int NB = (n + 255) / 256;
  const int CH = (NB + 511) / 512;

  // ws layout: csr | off | cur | bsum | bpre  (~7.8 MB)
  int* csr  = (int*)d_ws;
  int* off  = csr + E;
  int* cur  = off + (n + 1);
  int* bsum = cur + n;
  int* bpre = bsum + NB;

  hipLaunchKernelGGL(scan1_kernel, dim3(NB), dim3(256), 0, stream,
                     degree, off, bsum, n);
  hipLaunchKernelGGL(scan2_kernel, dim3(1), dim3(512), 0, stream,
                     bsum, bpre, off, NB, CH, n);
  hipLaunchKernelGGL(scan3_kernel, dim3(NB), dim3(256), 0, stream,
                     off, cur, bpre, n);
  hipLaunchKernelGGL(sort_kernel, dim3(4096), dim3(256), 0, stream,
                     ei, cur, csr, E);
  hipLaunchKernelGGL(gather_kernel, dim3(2048), dim3(256), 0, stream,
                     x, off, csr, degree, out, n);
  hipLaunchKernelGGL(out_kernel, dim3(1024), dim3(256), 0, stream,
                     x, fc_w, fc_b, dir_w, dir_b, neu_w, neu_b, rob_w, rob_b,
                     degree, out, n);
}

// Round 8
// 400.534 us; speedup vs baseline: 6.4169x; 1.4934x over previous
//
#include <hip/hip_runtime.h>

#define DIM 64
#define EPS 1e-8f

// ---------------------------------------------------------------------------
// Pipeline (CSR, no float atomics, no h materialization):
//   scan1/2/3 : exclusive scan of degree -> off[] (+cursor copy)
//   sort      : counting sort -> csr cols grouped by row (1 int atomic/edge)
//   gather    : z[i] = deg_i*x[i] + sum x[csr[j]]   -> written to d_out
//   out       : agg = z@fc_w^T + 2*deg*fc_b ; alpha/beta/gamma from x;
//               out = (relu(b)*agg + g)/(relu(a) + relu(b)*deg + EPS)
//
// Algebra: agg[i] = k_i*h[i] + sum h[col] with h = x@W^T + b and k_i ==
// degree[i], so agg[i] = z[i]@W^T + 2*deg_i*b with z = deg*x + sum x[col].
//
// Round-7 lesson (counters): wave-uniform global float4 loads of x/z rows are
// 16B/issue broadcast loads the compiler can't scalarize (threadIdx-derived
// address), and VGPR=256 capped residency at 2 waves/SIMD -> 327us at 15%
// VALUBusy / 2% HBM. This version: weights in REGISTERS (wave m owns matrix
// m, row `lane` = 64 VGPRs), src rows enter via ONE coalesced 256B load into
// lanes, and the k-broadcast is v_readlane (register op, zero mem latency).
// ---------------------------------------------------------------------------

__global__ __launch_bounds__(256) void scan1_kernel(
    const float* __restrict__ degree, int* __restrict__ off,
    int* __restrict__ bsum, int n)
{
  __shared__ int s[256];
  const int t = threadIdx.x;
  const int i = blockIdx.x * 256 + t;
  const int v = (i < n) ? (int)(degree[i] + 0.5f) : 0;
  s[t] = v;
  __syncthreads();
  for (int st = 1; st < 256; st <<= 1) {
    int a = (t >= st) ? s[t - st] : 0;
    __syncthreads();
    s[t] += a;
    __syncthreads();
  }
  if (i < n) off[i] = s[t] - v;
  if (t == 255) bsum[blockIdx.x] = s[t];
}

__global__ __launch_bounds__(512) void scan2_kernel(
    const int* __restrict__ bsum, int* __restrict__ bpre,
    int* __restrict__ off, int nb, int ch, int n)
{
  __shared__ int s[512];
  const int t = threadIdx.x;
  const int base = t * ch;
  int local = 0;
  for (int q = 0; q < ch; ++q) {
    const int j = base + q;
    if (j < nb) local += bsum[j];
  }
  s[t] = local;
  __syncthreads();
  for (int st = 1; st < 512; st <<= 1) {
    int a = (t >= st) ? s[t - st] : 0;
    __syncthreads();
    s[t] += a;
    __syncthreads();
  }
  int run = s[t] - local;
  for (int q = 0; q < ch; ++q) {
    const int j = base + q;
    if (j < nb) { bpre[j] = run; run += bsum[j]; }
  }
  if (t == 511) off[n] = s[511];
}

__global__ __launch_bounds__(256) void scan3_kernel(
    int* __restrict__ off, int* __restrict__ cur,
    const int* __restrict__ bpre, int n)
{
  const int i = blockIdx.x * 256 + threadIdx.x;
  if (i < n) {
    const int o = off[i] + bpre[blockIdx.x];
    off[i] = o;
    cur[i] = o;
  }
}

__global__ __launch_bounds__(256) void sort_kernel(
    const int* __restrict__ ei, int* __restrict__ cur,
    int* __restrict__ csr, int E)
{
  const int tid = blockIdx.x * 256 + threadIdx.x;
  const int stride = gridDim.x * 256;
  for (int e = tid; e < E; e += stride) {
    const int r = ei[e];
    const int c = ei[E + e];
    const int p = atomicAdd(&cur[r], 1);
    csr[p] = c;
  }
}

// z[i] = deg_i*x[i] + sum_j x[csr[j]]  — float4 lanes, 4 edges per wave-step.
__global__ __launch_bounds__(256, 8) void gather_kernel(
    const float* __restrict__ x, const int* __restrict__ off,
    const int* __restrict__ csr, const float* __restrict__ degree,
    float* __restrict__ z, int n)
{
  const int lane = threadIdx.x & 63;
  const int sub = lane >> 4;
  const int l16 = lane & 15;
  const int wid = (blockIdx.x << 2) + (threadIdx.x >> 6);
  const int nwaves = gridDim.x << 2;
  for (int node = wid; node < n; node += nwaves) {
    float4 acc = make_float4(0.f, 0.f, 0.f, 0.f);
    if (sub == 0) {
      const float4 xv = *(const float4*)&x[((size_t)node << 6) + (l16 << 2)];
      const float d = degree[node];
      acc.x = d * xv.x; acc.y = d * xv.y; acc.z = d * xv.z; acc.w = d * xv.w;
    }
    const int o0 = off[node];
    const int o1 = off[node + 1];
    int j = o0;
    for (; j + 8 <= o1; j += 8) {
      const int c0 = csr[j + sub];
      const int c1 = csr[j + 4 + sub];
      const float4 v0 = *(const float4*)&x[((size_t)c0 << 6) + (l16 << 2)];
      const float4 v1 = *(const float4*)&x[((size_t)c1 << 6) + (l16 << 2)];
      acc.x += v0.x + v1.x; acc.y += v0.y + v1.y;
      acc.z += v0.z + v1.z; acc.w += v0.w + v1.w;
    }
    if (j + 4 <= o1) {
      const int c = csr[j + sub];
      const float4 v = *(const float4*)&x[((size_t)c << 6) + (l16 << 2)];
      acc.x += v.x; acc.y += v.y; acc.z += v.z; acc.w += v.w;
      j += 4;
    }
    const int rem = o1 - j;
    if (sub < rem) {
      const int c = csr[j + sub];
      const float4 v = *(const float4*)&x[((size_t)c << 6) + (l16 << 2)];
      acc.x += v.x; acc.y += v.y; acc.z += v.z; acc.w += v.w;
    }
    acc.x += __shfl_xor(acc.x, 16, 64); acc.y += __shfl_xor(acc.y, 16, 64);
    acc.z += __shfl_xor(acc.z, 16, 64); acc.w += __shfl_xor(acc.w, 16, 64);
    acc.x += __shfl_xor(acc.x, 32, 64); acc.y += __shfl_xor(acc.y, 32, 64);
    acc.z += __shfl_xor(acc.z, 32, 64); acc.w += __shfl_xor(acc.w, 32, 64);
    if (sub == 0) {
      *(float4*)&z[((size_t)node << 6) + (l16 << 2)] = acc;
    }
  }
}

// Fused epilogue v3: wave m (of 4) owns matrix m = {fc,dir,neu,rob}[m], with
// row `lane` preloaded into 64 VGPRs. Per node: ONE coalesced 256B row load
// (z for m=0, x else); broadcast src[k] via v_readlane (no memory). Results
// staged in 16KB LDS; combine phase does relu/div and coalesced store.
// T=16 nodes per tile; grid-stride persistent so weights load once per block.
__global__ __launch_bounds__(256) void out_kernel(
    const float* __restrict__ x,
    const float* __restrict__ fc_w,  const float* __restrict__ fc_b,
    const float* __restrict__ dir_w, const float* __restrict__ dir_b,
    const float* __restrict__ neu_w, const float* __restrict__ neu_b,
    const float* __restrict__ rob_w, const float* __restrict__ rob_b,
    const float* __restrict__ degree, float* __restrict__ out, int n)
{
  __shared__ float res_lds[4][16][DIM];   // 16 KB
  __shared__ float fcb_lds[DIM];
  const int t = threadIdx.x;
  const int m = t >> 6;                   // wave id = matrix id
  const int lane = t & 63;

  const float* wm = (m == 0) ? fc_w : (m == 1) ? dir_w
                  : (m == 2) ? neu_w : rob_w;
  const float* bm = (m == 0) ? fc_b : (m == 1) ? dir_b
                  : (m == 2) ? neu_b : rob_b;
  if (t < DIM) fcb_lds[t] = fc_b[t];

  // preload W_m row `lane` into registers (64 VGPRs, all static indices)
  float wreg[64];
  const float* wrow = wm + lane * DIM;
#pragma unroll
  for (int k4 = 0; k4 < 16; ++k4) {
    const float4 w = *(const float4*)&wrow[k4 << 2];
    wreg[(k4 << 2) + 0] = w.x; wreg[(k4 << 2) + 1] = w.y;
    wreg[(k4 << 2) + 2] = w.z; wreg[(k4 << 2) + 3] = w.w;
  }
  const float bias = bm[lane];
  const float* srcbase = (m == 0) ? out : x;   // z lives in d_out
  __syncthreads();

  const int ntiles = (n + 15) >> 4;
  for (int tile = blockIdx.x; tile < ntiles; tile += gridDim.x) {
    const int node0 = tile << 4;
    const int cnt = (n - node0 < 16) ? (n - node0) : 16;

    // phase 1: each wave computes its matvec for the tile's nodes,
    // prefetch-1 on the coalesced src-row load to hide L2/L3 latency.
    float v = srcbase[((size_t)node0 << 6) | lane];
    for (int i = 0; i < cnt; ++i) {
      float vn = 0.f;
      if (i + 1 < cnt) vn = srcbase[((size_t)(node0 + i + 1) << 6) | lane];
      const int vi = __float_as_int(v);
      float a0 = 0.f, a1 = 0.f, a2 = 0.f, a3 = 0.f;
#pragma unroll
      for (int k = 0; k < 64; k += 4) {
        a0 = fmaf(wreg[k + 0],
                  __int_as_float(__builtin_amdgcn_readlane(vi, k + 0)), a0);
        a1 = fmaf(wreg[k + 1],
                  __int_as_float(__builtin_amdgcn_readlane(vi, k + 1)), a1);
        a2 = fmaf(wreg[k + 2],
                  __int_as_float(__builtin_amdgcn_readlane(vi, k + 2)), a2);
        a3 = fmaf(wreg[k + 3],
                  __int_as_float(__builtin_amdgcn_readlane(vi, k + 3)), a3);
      }
      float r = (a0 + a1) + (a2 + a3);
      if (m != 0) r += bias;              // fc bias needs deg: folded in combine
      res_lds[m][i][lane] = r;
      v = vn;
    }
    __syncthreads();

    // phase 2: combine + store (coalesced; threads cover 16x64 elems)
#pragma unroll
    for (int e = 0; e < 4; ++e) {
      const int idx = (e << 8) + t;
      const int i = idx >> 6;
      const int d = idx & 63;
      const int node = node0 + i;
      if (i < cnt) {
        const float deg = degree[node];
        const float agg = res_lds[0][i][d] + 2.f * deg * fcb_lds[d];
        const float al = fmaxf(res_lds[1][i][d], 0.f);
        const float be = fmaxf(res_lds[2][i][d], 0.f);
        const float ga = res_lds[3][i][d];
        out[((size_t)node << 6) | d] =
            fmaf(be, agg, ga) / (fmaf(be, deg, al) + EPS);
      }
    }
    __syncthreads();                      // res_lds reused next tile
  }
}

extern "C" void kernel_launch(void* const* d_in, const int* in_sizes, int n_in,
                              void* d_out, int out_size, void* d_ws, size_t ws_size,
                              hipStream_t stream) {
  const float* x      = (const float*)d_in[0];
  const int*   ei     = (const int*)  d_in[1];
  const float* degree = (const float*)d_in[2];
  const float* fc_w   = (const float*)d_in[3];
  const float* fc_b   = (const float*)d_in[4];
  const float* dir_w  = (const float*)d_in[5];
  const float* dir_b  = (const float*)d_in[6];
  const float* neu_w  = (const float*)d_in[7];
  const float* neu_b  = (const float*)d_in[8];
  const float* rob_w  = (const float*)d_in[9];
  const float* rob_b  = (const float*)d_in[10];
  float* out = (float*)d_out;

  const int n = in_sizes[0] / DIM;
  const int E = in_sizes[1] / 2;
  const int NB = (n + 255) / 256;
  const int CH = (NB + 511) / 512;

  // ws layout: csr | off | cur | bsum | bpre  (~7.8 MB)
  int* csr  = (int*)d_ws;
  int* off  = csr + E;
  int* cur  = off + (n + 1);
  int* bsum = cur + n;
  int* bpre = bsum + NB;

  hipLaunchKernelGGL(scan1_kernel, dim3(NB), dim3(256), 0, stream,
                     degree, off, bsum, n);
  hipLaunchKernelGGL(scan2_kernel, dim3(1), dim3(512), 0, stream,
                     bsum, bpre, off, NB, CH, n);
  hipLaunchKernelGGL(scan3_kernel, dim3(NB), dim3(256), 0, stream,
                     off, cur, bpre, n);
  hipLaunchKernelGGL(sort_kernel, dim3(4096), dim3(256), 0, stream,
                     ei, cur, csr, E);
  hipLaunchKernelGGL(gather_kernel, dim3(2048), dim3(256), 0, stream,
                     x, off, csr, degree, out, n);
  hipLaunchKernelGGL(out_kernel, dim3(1536), dim3(256), 0, stream,
                     x, fc_w, fc_b, dir_w, dir_b, neu_w, neu_b, rob_w, rob_b,
                     degree, out, n);
}